// Round 10
// baseline (369.819 us; speedup 1.0000x reference)
//
#include <hip/hip_runtime.h>

// DeepFM fused ranker, fp32.
// R13: halve the LDS-pipe load. Arithmetic on R12's ~45us: phase B+C issue
// ~4200 ds_read_b128/CU x 12cyc ~ 21us on the per-CU LDS pipe (acts broadcast-
// read 16x; count invariant under jp/rh retiling). Fix = R6's 4-neuron/lane
// tile (VGPR 76, exonerated — its 107us was grid-512 occupancy, since fixed)
// on R12's proven geometry (ROWS16/grid1024/256t + lane-parallel phase A):
//  - Phase B: jg=lane&7 (4 neurons), rg=lane>>3 (rows rg,rg+8): 2 act b128/k4
//    (banks 12rg mod 32 = disjoint full cover) + 4 weight b128 (L2 pipe).
//  - Phase C: jq=lane&3, rq=lane>>2 (1 row): 1 act b128/k4 (2-way alias, free).
//  Block LDS instrs 1056 -> 528. Same VALU. Phase A/D = R12.

typedef float v2f __attribute__((ext_vector_type(2)));
static __device__ __forceinline__ v2f bc2(float x) { v2f r; r.x = x; r.y = x; return r; }
static __device__ __forceinline__ float relu1(float x) { return fmaxf(x, 0.f); }

#define ROWS_PER_BLOCK 16
#define ROWS_PER_WAVE 4
#define DI_STRIDE 204            // floats; 51 float4
#define H1_STRIDE 132            // floats; 33 float4

// ---- pre-pass: pair-transposed packed weights, 4-neuron-group major ----
// W1p[(g*50 + k4)*4 + q], g=0..31, q=p*2+s: {W1[j][c],W1[j+1][c],W1[j][c+1],
//   W1[j+1][c+1]}, j=g*4+2p, c=4*k4+2s.  W2p likewise, g=0..15, row len 128.
__global__ void pack_weights(const float* __restrict__ W1, const float* __restrict__ W2,
                             float4* __restrict__ W1p, float4* __restrict__ W2p) {
    const int idx = blockIdx.x * blockDim.x + threadIdx.x;
    if (idx < 6400) {
        const int q = idx & 3, t = idx >> 2;
        const int k4 = t % 50, g = t / 50;
        const int j = g * 4 + 2 * (q >> 1), c = 4 * k4 + 2 * (q & 1);
        W1p[idx] = make_float4(W1[j * 200 + c],     W1[(j + 1) * 200 + c],
                               W1[j * 200 + c + 1], W1[(j + 1) * 200 + c + 1]);
    }
    if (idx < 2048) {
        const int q = idx & 3, t = idx >> 2;
        const int k4 = t & 31, g = t >> 5;
        const int j = g * 4 + 2 * (q >> 1), c = 4 * k4 + 2 * (q & 1);
        W2p[idx] = make_float4(W2[j * 128 + c],     W2[(j + 1) * 128 + c],
                               W2[j * 128 + c + 1], W2[(j + 1) * 128 + c + 1]);
    }
}

__global__ __launch_bounds__(256) void deepfm_kernel(
    const int* __restrict__ user_id, const int* __restrict__ item_id,
    const int* __restrict__ gender_, const int* __restrict__ age_,
    const int* __restrict__ occ_, const int* __restrict__ genre_ids,
    const float* __restrict__ genre_mask, const float* __restrict__ dense,
    const float* __restrict__ fo_user, const float* __restrict__ fo_item,
    const float* __restrict__ fo_gender, const float* __restrict__ fo_age,
    const float* __restrict__ fo_occ, const float* __restrict__ fo_genre,
    const float* __restrict__ emb_user, const float* __restrict__ emb_item,
    const float* __restrict__ emb_gender, const float* __restrict__ emb_age,
    const float* __restrict__ emb_occ, const float* __restrict__ emb_genre,
    const float* __restrict__ dense_W, const float* __restrict__ dense_b,
    const float4* __restrict__ W1p, const float* __restrict__ b1,
    const float4* __restrict__ W2p, const float* __restrict__ b2,
    const float* __restrict__ Wout, const float* __restrict__ bout,
    float* __restrict__ out, int B)
{
    __shared__ float lds_di[ROWS_PER_BLOCK][DI_STRIDE];   // 13.1 KB; h1[16][132] overlays
    __shared__ float lds_rs[ROWS_PER_BLOCK];
    __shared__ float lds_part[ROWS_PER_BLOCK][4];

    const int tid = threadIdx.x;
    const int wid = tid >> 6;
    const int lane = tid & 63;
    const int blockRow0 = blockIdx.x * ROWS_PER_BLOCK;

    // ---------------- Phase A: 4 rows x 16 dim-pairs, fully concurrent (R12) ------
    {
        const int rl = lane & 3;          // row within wave
        const int dx = lane >> 2;         // dim-pair index 0..15
        const int d0 = 2 * dx;            // dims {d0, d0+1}

        int row = blockRow0 + wid * ROWS_PER_WAVE + rl;
        if (row >= B) row = B - 1;
        const int ri = wid * ROWS_PER_WAVE + rl;

        const int uid = user_id[row], iid = item_id[row];
        const int gg = gender_[row], aa = age_[row], oo = occ_[row];

        int gid[6]; float mk[6]; float msum = 0.f;
        #pragma unroll
        for (int t = 0; t < 6; ++t) {
            gid[t] = genre_ids[row * 6 + t];
            mk[t]  = genre_mask[row * 6 + t];
            msum  += mk[t];
        }
        const float inv_den = 1.0f / fmaxf(msum, 1.0f);

        const float2 eu = *reinterpret_cast<const float2*>(emb_user + (size_t)uid * 32 + d0);
        const float2 ei = *reinterpret_cast<const float2*>(emb_item + (size_t)iid * 32 + d0);
        const float2 eg = *reinterpret_cast<const float2*>(emb_gender + gg * 32 + d0);
        const float2 ea = *reinterpret_cast<const float2*>(emb_age + aa * 32 + d0);
        const float2 eo = *reinterpret_cast<const float2*>(emb_occ + oo * 32 + d0);
        float epx = 0.f, epy = 0.f;
        #pragma unroll
        for (int t = 0; t < 6; ++t) {
            const float2 g = *reinterpret_cast<const float2*>(emb_genre + gid[t] * 32 + d0);
            epx += mk[t] * g.x; epy += mk[t] * g.y;
        }
        epx *= inv_den; epy *= inv_den;

        *reinterpret_cast<float2*>(&lds_di[ri][d0])       = eu;
        *reinterpret_cast<float2*>(&lds_di[ri][32 + d0])  = ei;
        *reinterpret_cast<float2*>(&lds_di[ri][64 + d0])  = eg;
        *reinterpret_cast<float2*>(&lds_di[ri][96 + d0])  = ea;
        *reinterpret_cast<float2*>(&lds_di[ri][128 + d0]) = eo;
        *reinterpret_cast<float2*>(&lds_di[ri][160 + d0]) = make_float2(epx, epy);

        const float sx = eu.x + ei.x + eg.x + ea.x + eo.x + epx;
        const float sy = eu.y + ei.y + eg.y + ea.y + eo.y + epy;
        const float qx = eu.x*eu.x + ei.x*ei.x + eg.x*eg.x + ea.x*ea.x + eo.x*eo.x + epx*epx;
        const float qy = eu.y*eu.y + ei.y*ei.y + eg.y*eg.y + ea.y*ea.y + eo.y*eo.y + epy*epy;
        float c = 0.5f * ((sx * sx - qx) + (sy * sy - qy));

        if (dx < 4) {
            const float2 dv = *reinterpret_cast<const float2*>(dense + (size_t)row * 8 + d0);
            *reinterpret_cast<float2*>(&lds_di[ri][192 + d0]) = dv;
            c += dv.x * dense_W[d0] + dv.y * dense_W[d0 + 1];
        } else if (dx == 8)  c += fo_user[uid];
        else if (dx == 9)  c += fo_item[iid];
        else if (dx == 10) c += fo_gender[gg];
        else if (dx == 11) c += fo_age[aa];
        else if (dx == 12) c += fo_occ[oo];
        else if (dx == 13) {
            float fg = 0.f;
            #pragma unroll
            for (int t = 0; t < 6; ++t) fg += mk[t] * fo_genre[gid[t]];
            c += fg * inv_den;
        } else if (dx == 14) c += dense_b[0];

        c += __shfl_xor(c, 4); c += __shfl_xor(c, 8);
        c += __shfl_xor(c, 16); c += __shfl_xor(c, 32);
        if (dx == 0) lds_rs[ri] = c;
    }
    __syncthreads();

    // ---------------- Phase B: h1 = relu(deep_in @ W1^T + b1) ----------------------
    // wave owns neurons [32*wid, 32*wid+32) as 8 groups of 4; jg=lane&7 -> group,
    // rg=lane>>3 -> rows {rg, rg+8}. Per k4: 2 act b128 (full 32-bank cover,
    // 8-lane broadcast) + 4 weight b128 (L2 stream) + 16 v_pk_fma.
    const int jg = lane & 7;
    const int rg = lane >> 3;

    v2f acc[2][2];
    acc[0][0] = bc2(0.f); acc[0][1] = bc2(0.f);
    acc[1][0] = bc2(0.f); acc[1][1] = bc2(0.f);

    {
        const float4* __restrict__ W1b = W1p + (wid * 8 + jg) * 200;
        const float4* __restrict__ dv = reinterpret_cast<const float4*>(&lds_di[0][0]); // stride 51

        #pragma unroll 2
        for (int k4 = 0; k4 < 50; ++k4) {
            const float4 wa0 = W1b[k4 * 4 + 0];   // pair0 {j0k0,j1k0,j0k1,j1k1}
            const float4 wa1 = W1b[k4 * 4 + 1];   // pair0 k2,k3
            const float4 wb0 = W1b[k4 * 4 + 2];   // pair1 k0,k1
            const float4 wb1 = W1b[k4 * 4 + 3];   // pair1 k2,k3
            const v2f p00 = { wa0.x, wa0.y }, p01 = { wa0.z, wa0.w };
            const v2f p02 = { wa1.x, wa1.y }, p03 = { wa1.z, wa1.w };
            const v2f p10 = { wb0.x, wb0.y }, p11 = { wb0.z, wb0.w };
            const v2f p12 = { wb1.x, wb1.y }, p13 = { wb1.z, wb1.w };
            #pragma unroll
            for (int r = 0; r < 2; ++r) {
                const float4 a = dv[(rg + 8 * r) * 51 + k4];
                acc[r][0] = __builtin_elementwise_fma(p00, bc2(a.x), acc[r][0]);
                acc[r][0] = __builtin_elementwise_fma(p01, bc2(a.y), acc[r][0]);
                acc[r][0] = __builtin_elementwise_fma(p02, bc2(a.z), acc[r][0]);
                acc[r][0] = __builtin_elementwise_fma(p03, bc2(a.w), acc[r][0]);
                acc[r][1] = __builtin_elementwise_fma(p10, bc2(a.x), acc[r][1]);
                acc[r][1] = __builtin_elementwise_fma(p11, bc2(a.y), acc[r][1]);
                acc[r][1] = __builtin_elementwise_fma(p12, bc2(a.z), acc[r][1]);
                acc[r][1] = __builtin_elementwise_fma(p13, bc2(a.w), acc[r][1]);
            }
        }
    }
    __syncthreads();   // all deep_in reads done; overlay h1

    float* __restrict__ h1b = &lds_di[0][0];   // h1[row][j] at row*132 + j
    {
        const int j0 = wid * 32 + 4 * jg;
        const float4 bb = *reinterpret_cast<const float4*>(b1 + j0);
        #pragma unroll
        for (int r = 0; r < 2; ++r) {
            const int row = rg + 8 * r;
            *reinterpret_cast<float4*>(h1b + row * H1_STRIDE + j0) =
                make_float4(relu1(acc[r][0].x + bb.x), relu1(acc[r][0].y + bb.y),
                            relu1(acc[r][1].x + bb.z), relu1(acc[r][1].y + bb.w));
        }
    }
    __syncthreads();

    // ---------------- Phase C: h2 = relu(h1 @ W2^T + b2) ---------------------------
    // wave owns neurons [16*wid,16*wid+16) as 4 groups of 4; jq=lane&3 -> group,
    // rq=lane>>2 -> 1 row. Per k4: 1 act b128 (2-way alias, free) + 4 weight b128
    // + 8 v_pk_fma.
    const int jq = lane & 3;
    const int rq = lane >> 2;

    v2f acc2[2];
    acc2[0] = bc2(0.f); acc2[1] = bc2(0.f);

    {
        const float4* __restrict__ W2b = W2p + (wid * 4 + jq) * 128;
        const float4* __restrict__ h1v = reinterpret_cast<const float4*>(h1b); // stride 33

        #pragma unroll 2
        for (int k4 = 0; k4 < 32; ++k4) {
            const float4 wa0 = W2b[k4 * 4 + 0];
            const float4 wa1 = W2b[k4 * 4 + 1];
            const float4 wb0 = W2b[k4 * 4 + 2];
            const float4 wb1 = W2b[k4 * 4 + 3];
            const v2f p00 = { wa0.x, wa0.y }, p01 = { wa0.z, wa0.w };
            const v2f p02 = { wa1.x, wa1.y }, p03 = { wa1.z, wa1.w };
            const v2f p10 = { wb0.x, wb0.y }, p11 = { wb0.z, wb0.w };
            const v2f p12 = { wb1.x, wb1.y }, p13 = { wb1.z, wb1.w };
            const float4 h = h1v[rq * 33 + k4];
            acc2[0] = __builtin_elementwise_fma(p00, bc2(h.x), acc2[0]);
            acc2[0] = __builtin_elementwise_fma(p01, bc2(h.y), acc2[0]);
            acc2[0] = __builtin_elementwise_fma(p02, bc2(h.z), acc2[0]);
            acc2[0] = __builtin_elementwise_fma(p03, bc2(h.w), acc2[0]);
            acc2[1] = __builtin_elementwise_fma(p10, bc2(h.x), acc2[1]);
            acc2[1] = __builtin_elementwise_fma(p11, bc2(h.y), acc2[1]);
            acc2[1] = __builtin_elementwise_fma(p12, bc2(h.z), acc2[1]);
            acc2[1] = __builtin_elementwise_fma(p13, bc2(h.w), acc2[1]);
        }
    }

    // ---------------- Phase D: Wout dot + combine ----------------------------------
    {
        const int j0 = wid * 16 + 4 * jq;
        const float4 bb2 = *reinterpret_cast<const float4*>(b2 + j0);
        const float4 wo  = *reinterpret_cast<const float4*>(Wout + j0);
        const float h0 = relu1(acc2[0].x + bb2.x);
        const float h1x = relu1(acc2[0].y + bb2.y);
        const float h2x = relu1(acc2[1].x + bb2.z);
        const float h3x = relu1(acc2[1].y + bb2.w);
        float v = wo.x * h0 + wo.y * h1x + wo.z * h2x + wo.w * h3x;
        v += __shfl_xor(v, 1); v += __shfl_xor(v, 2);
        if (jq == 0) lds_part[rq][wid] = v;
    }
    __syncthreads();

    if (tid < ROWS_PER_BLOCK) {
        const int row = blockRow0 + tid;
        if (row < B) {
            const float deep = lds_part[tid][0] + lds_part[tid][1]
                             + lds_part[tid][2] + lds_part[tid][3] + bout[0];
            out[row] = deep + lds_rs[tid];
        }
    }
}

extern "C" void kernel_launch(void* const* d_in, const int* in_sizes, int n_in,
                              void* d_out, int out_size, void* d_ws, size_t ws_size,
                              hipStream_t stream) {
    const int B = in_sizes[0];

    float4* W1p = reinterpret_cast<float4*>(d_ws);                  // 6400 float4 = 100 KB
    float4* W2p = reinterpret_cast<float4*>((char*)d_ws + 102400);  // 2048 float4 = 32 KB

    pack_weights<<<25, 256, 0, stream>>>(
        (const float*)d_in[22], (const float*)d_in[24], W1p, W2p);

    const int grid = (B + ROWS_PER_BLOCK - 1) / ROWS_PER_BLOCK;  // 1024 at B=16384
    deepfm_kernel<<<grid, 256, 0, stream>>>(
        (const int*)d_in[0],  (const int*)d_in[1],  (const int*)d_in[2],
        (const int*)d_in[3],  (const int*)d_in[4],  (const int*)d_in[5],
        (const float*)d_in[6],  (const float*)d_in[7],
        (const float*)d_in[8],  (const float*)d_in[9],  (const float*)d_in[10],
        (const float*)d_in[11], (const float*)d_in[12], (const float*)d_in[13],
        (const float*)d_in[14], (const float*)d_in[15], (const float*)d_in[16],
        (const float*)d_in[17], (const float*)d_in[18], (const float*)d_in[19],
        (const float*)d_in[20], (const float*)d_in[21],
        W1p, (const float*)d_in[23],
        W2p, (const float*)d_in[25],
        (const float*)d_in[26], (const float*)d_in[27],
        (float*)d_out, B);
}

// Round 11
// 263.114 us; speedup vs baseline: 1.4055x; 1.4055x over previous
//
#include <hip/hip_runtime.h>

// DeepFM fused ranker, fp32.
// R14: halve act LDS reads WITHOUT touching the weight stream. R13's lesson:
// lane-dependent weight bases -> broadcast scattered loads -> VGPR 36, serial
// L2 round-trips, 3.5x regression. The coalesced wave-uniform weight stream
// (R12) is load-bearing. So: keep R12's phase-B/C lane maps verbatim and halve
// ROWS instead (8/block, grid 2048): rh covers {rh, rh+4} -> 2 act b128/k4 in
// B (was 4), 1 in C (was 2). Phase A: 2 rows/wave, rl=lane&1, d=lane>>1, one
// dim/lane, all 11 gathers in one latency window (R12 structure, scalar width).
// LDS 6.7KB -> up to 8 blocks/CU.

typedef float v2f __attribute__((ext_vector_type(2)));
static __device__ __forceinline__ v2f bc2(float x) { v2f r; r.x = x; r.y = x; return r; }
static __device__ __forceinline__ float relu1(float x) { return fmaxf(x, 0.f); }

#define ROWS_PER_BLOCK 8
#define ROWS_PER_WAVE 2
#define DI_STRIDE 204            // floats; 51 float4
#define H1_STRIDE 132            // floats; 33 float4

// ---- pre-pass: pair-transposed packed weights (R4/R12 layout, unchanged) ----
// W1p[((wid*50+k4)*16+jp)*2+s] = {W1[j0][c],W1[j1][c],W1[j0][c+1],W1[j1][c+1]}
//   j0 = 32*wid + 2*jp, c = 4*k4 + 2*s
// W2p[((wid*32+k4)*8+jp)*2+s]  = same with j0 = 16*wid + 2*jp, row len 128
__global__ void pack_weights(const float* __restrict__ W1, const float* __restrict__ W2,
                             float4* __restrict__ W1p, float4* __restrict__ W2p) {
    const int idx = blockIdx.x * blockDim.x + threadIdx.x;
    if (idx < 6400) {
        const int s = idx & 1, jp = (idx >> 1) & 15, k4 = (idx >> 5) % 50, w = idx / 1600;
        const int j0 = w * 32 + 2 * jp, c = 4 * k4 + 2 * s;
        W1p[idx] = make_float4(W1[j0 * 200 + c],     W1[(j0 + 1) * 200 + c],
                               W1[j0 * 200 + c + 1], W1[(j0 + 1) * 200 + c + 1]);
    }
    if (idx < 2048) {
        const int s = idx & 1, jp = (idx >> 1) & 7, k4 = (idx >> 4) & 31, w = idx >> 9;
        const int j0 = w * 16 + 2 * jp, c = 4 * k4 + 2 * s;
        W2p[idx] = make_float4(W2[j0 * 128 + c],     W2[(j0 + 1) * 128 + c],
                               W2[j0 * 128 + c + 1], W2[(j0 + 1) * 128 + c + 1]);
    }
}

__global__ __launch_bounds__(256) void deepfm_kernel(
    const int* __restrict__ user_id, const int* __restrict__ item_id,
    const int* __restrict__ gender_, const int* __restrict__ age_,
    const int* __restrict__ occ_, const int* __restrict__ genre_ids,
    const float* __restrict__ genre_mask, const float* __restrict__ dense,
    const float* __restrict__ fo_user, const float* __restrict__ fo_item,
    const float* __restrict__ fo_gender, const float* __restrict__ fo_age,
    const float* __restrict__ fo_occ, const float* __restrict__ fo_genre,
    const float* __restrict__ emb_user, const float* __restrict__ emb_item,
    const float* __restrict__ emb_gender, const float* __restrict__ emb_age,
    const float* __restrict__ emb_occ, const float* __restrict__ emb_genre,
    const float* __restrict__ dense_W, const float* __restrict__ dense_b,
    const float4* __restrict__ W1p, const float* __restrict__ b1,
    const float4* __restrict__ W2p, const float* __restrict__ b2,
    const float* __restrict__ Wout, const float* __restrict__ bout,
    float* __restrict__ out, int B)
{
    __shared__ float lds_di[ROWS_PER_BLOCK][DI_STRIDE];   // 6.5 KB; h1[8][132] overlays
    __shared__ float lds_rs[ROWS_PER_BLOCK];
    __shared__ float lds_part[ROWS_PER_BLOCK][4];

    const int tid = threadIdx.x;
    const int wid = tid >> 6;
    const int lane = tid & 63;
    const int blockRow0 = blockIdx.x * ROWS_PER_BLOCK;

    // ---------------- Phase A: 2 rows x 32 dims, fully concurrent ------------------
    {
        const int rl = lane & 1;          // row within wave
        const int d  = lane >> 1;         // dim 0..31

        int row = blockRow0 + wid * ROWS_PER_WAVE + rl;
        if (row >= B) row = B - 1;
        const int ri = wid * ROWS_PER_WAVE + rl;

        const int uid = user_id[row], iid = item_id[row];
        const int gg = gender_[row], aa = age_[row], oo = occ_[row];

        int gid[6]; float mk[6]; float msum = 0.f;
        #pragma unroll
        for (int t = 0; t < 6; ++t) {
            gid[t] = genre_ids[row * 6 + t];
            mk[t]  = genre_mask[row * 6 + t];
            msum  += mk[t];
        }
        const float inv_den = 1.0f / fmaxf(msum, 1.0f);

        // 11 independent scalar gathers — one latency window for both rows
        const float eu = emb_user[(size_t)uid * 32 + d];
        const float ei = emb_item[(size_t)iid * 32 + d];
        const float eg = emb_gender[gg * 32 + d];
        const float ea = emb_age[aa * 32 + d];
        const float eo = emb_occ[oo * 32 + d];
        float ep = 0.f;
        #pragma unroll
        for (int t = 0; t < 6; ++t) ep += mk[t] * emb_genre[gid[t] * 32 + d];
        ep *= inv_den;

        // deep_in layout: user | item | gender | age | occ | genre | dense
        lds_di[ri][d]        = eu;
        lds_di[ri][32 + d]   = ei;
        lds_di[ri][64 + d]   = eg;
        lds_di[ri][96 + d]   = ea;
        lds_di[ri][128 + d]  = eo;
        lds_di[ri][160 + d]  = ep;

        // FM second order: per-lane over its 1 dim
        const float s = eu + ei + eg + ea + eo + ep;
        const float q = eu*eu + ei*ei + eg*eg + ea*ea + eo*eo + ep*ep;
        float c = 0.5f * (s * s - q);

        // distributed first-order + dense across spare d lanes
        if (d < 8) {
            const float dv = dense[(size_t)row * 8 + d];
            lds_di[ri][192 + d] = dv;
            c += dv * dense_W[d];
        } else if (d == 8)  c += fo_user[uid];
        else if (d == 9)  c += fo_item[iid];
        else if (d == 10) c += fo_gender[gg];
        else if (d == 11) c += fo_age[aa];
        else if (d == 12) c += fo_occ[oo];
        else if (d == 13) {
            float fg = 0.f;
            #pragma unroll
            for (int t = 0; t < 6; ++t) fg += mk[t] * fo_genre[gid[t]];
            c += fg * inv_den;
        } else if (d == 14) c += dense_b[0];

        // reduce across the 32 d-lanes (bits 1..5); rl (bit 0) preserved
        c += __shfl_xor(c, 2); c += __shfl_xor(c, 4); c += __shfl_xor(c, 8);
        c += __shfl_xor(c, 16); c += __shfl_xor(c, 32);
        if (d == 0) lds_rs[ri] = c;
    }
    __syncthreads();

    // ---------------- Phase B: h1 = relu(deep_in @ W1^T + b1) ----------------------
    // R12 lane map verbatim: jp1=lane&15 -> neuron pair (coalesced uniform-base
    // weight stream), rh=lane>>4 -> rows {rh, rh+4}. Per k4: 2 act b128
    // (8 distinct rows over the 2 instrs, banks 12*row mod 32 disjoint -> 0-conf)
    // + 2 weight b128 + 16 v_pk_fma.
    const int jp1 = lane & 15;
    const int rh  = lane >> 4;

    v2f acc[ROWS_PER_WAVE];
    acc[0] = bc2(0.f); acc[1] = bc2(0.f);

    {
        const float4* __restrict__ W1b = W1p + wid * 1600;
        const float4* __restrict__ dv = reinterpret_cast<const float4*>(&lds_di[0][0]); // stride 51

        #pragma unroll 2
        for (int k4 = 0; k4 < 50; ++k4) {
            const float4 wa = W1b[(k4 * 16 + jp1) * 2 + 0];   // {j0k0,j1k0,j0k1,j1k1}
            const float4 wb = W1b[(k4 * 16 + jp1) * 2 + 1];   // {j0k2,j1k2,j0k3,j1k3}
            const v2f w0 = { wa.x, wa.y }, w1 = { wa.z, wa.w };
            const v2f w2 = { wb.x, wb.y }, w3 = { wb.z, wb.w };
            #pragma unroll
            for (int r = 0; r < ROWS_PER_WAVE; ++r) {
                const float4 a = dv[(rh + 4 * r) * 51 + k4];
                acc[r] = __builtin_elementwise_fma(w0, bc2(a.x), acc[r]);
                acc[r] = __builtin_elementwise_fma(w1, bc2(a.y), acc[r]);
                acc[r] = __builtin_elementwise_fma(w2, bc2(a.z), acc[r]);
                acc[r] = __builtin_elementwise_fma(w3, bc2(a.w), acc[r]);
            }
        }
    }
    __syncthreads();   // all deep_in reads done; overlay h1

    float* __restrict__ h1b = &lds_di[0][0];   // h1[row][j] at row*132 + j
    {
        const int j0 = wid * 32 + 2 * jp1;
        const float2 bb = *reinterpret_cast<const float2*>(b1 + j0);
        #pragma unroll
        for (int r = 0; r < ROWS_PER_WAVE; ++r) {
            const int row = rh + 4 * r;
            reinterpret_cast<float2*>(h1b)[(row * H1_STRIDE + j0) >> 1] =
                make_float2(relu1(acc[r].x + bb.x), relu1(acc[r].y + bb.y));
        }
    }
    __syncthreads();

    // ---------------- Phase C: h2 = relu(h1 @ W2^T + b2) ---------------------------
    // jp2=lane&7 -> pair (coalesced weights), rh2=lane>>3 -> 1 row. Per k4:
    // 1 act b128 (8 addrs, banks 4*rh2 mod 32 distinct -> 0-conf) + 2 weight b128
    // + 8 v_pk_fma.
    const int jp2 = lane & 7;
    const int rh2 = lane >> 3;

    v2f acc2 = bc2(0.f);

    {
        const float4* __restrict__ W2b = W2p + wid * 512;
        const float4* __restrict__ h1v = reinterpret_cast<const float4*>(h1b); // stride 33

        #pragma unroll 2
        for (int k4 = 0; k4 < 32; ++k4) {
            const float4 wa = W2b[(k4 * 8 + jp2) * 2 + 0];
            const float4 wb = W2b[(k4 * 8 + jp2) * 2 + 1];
            const v2f w0 = { wa.x, wa.y }, w1 = { wa.z, wa.w };
            const v2f w2 = { wb.x, wb.y }, w3 = { wb.z, wb.w };
            const float4 h = h1v[rh2 * 33 + k4];
            acc2 = __builtin_elementwise_fma(w0, bc2(h.x), acc2);
            acc2 = __builtin_elementwise_fma(w1, bc2(h.y), acc2);
            acc2 = __builtin_elementwise_fma(w2, bc2(h.z), acc2);
            acc2 = __builtin_elementwise_fma(w3, bc2(h.w), acc2);
        }
    }

    // ---------------- Phase D: Wout dot + combine ----------------------------------
    {
        const int j0 = wid * 16 + 2 * jp2;
        const float2 bb2 = *reinterpret_cast<const float2*>(b2 + j0);
        const float2 wo  = *reinterpret_cast<const float2*>(Wout + j0);
        const float h2x = relu1(acc2.x + bb2.x);
        const float h2y = relu1(acc2.y + bb2.y);
        float v = wo.x * h2x + wo.y * h2y;
        v += __shfl_xor(v, 1); v += __shfl_xor(v, 2); v += __shfl_xor(v, 4);
        if (jp2 == 0) lds_part[rh2][wid] = v;
    }
    __syncthreads();

    if (tid < ROWS_PER_BLOCK) {
        const int row = blockRow0 + tid;
        if (row < B) {
            const float deep = lds_part[tid][0] + lds_part[tid][1]
                             + lds_part[tid][2] + lds_part[tid][3] + bout[0];
            out[row] = deep + lds_rs[tid];
        }
    }
}

extern "C" void kernel_launch(void* const* d_in, const int* in_sizes, int n_in,
                              void* d_out, int out_size, void* d_ws, size_t ws_size,
                              hipStream_t stream) {
    const int B = in_sizes[0];

    float4* W1p = reinterpret_cast<float4*>(d_ws);                  // 6400 float4 = 100 KB
    float4* W2p = reinterpret_cast<float4*>((char*)d_ws + 102400);  // 2048 float4 = 32 KB

    pack_weights<<<25, 256, 0, stream>>>(
        (const float*)d_in[22], (const float*)d_in[24], W1p, W2p);

    const int grid = (B + ROWS_PER_BLOCK - 1) / ROWS_PER_BLOCK;  // 2048 at B=16384
    deepfm_kernel<<<grid, 256, 0, stream>>>(
        (const int*)d_in[0],  (const int*)d_in[1],  (const int*)d_in[2],
        (const int*)d_in[3],  (const int*)d_in[4],  (const int*)d_in[5],
        (const float*)d_in[6],  (const float*)d_in[7],
        (const float*)d_in[8],  (const float*)d_in[9],  (const float*)d_in[10],
        (const float*)d_in[11], (const float*)d_in[12], (const float*)d_in[13],
        (const float*)d_in[14], (const float*)d_in[15], (const float*)d_in[16],
        (const float*)d_in[17], (const float*)d_in[18], (const float*)d_in[19],
        (const float*)d_in[20], (const float*)d_in[21],
        W1p, (const float*)d_in[23],
        W2p, (const float*)d_in[25],
        (const float*)d_in[26], (const float*)d_in[27],
        (float*)d_out, B);
}